// Round 1
// baseline (66.507 us; speedup 1.0000x reference)
//
#include <hip/hip_runtime.h>

// Problem constants (from reference setup_inputs)
constexpr int B  = 2;
constexpr int Ci = 32;
constexpr int K  = 9;   // 3x3
constexpr int Co = 32;
constexpr int H  = 64;
constexpr int W  = 64;

// out[b,o,h,w] = sum_{c,k} x[b,c,h+kh-1,w+kw-1] * wt[b,c,k,o,h,w]
// weights layout: ((((b*Ci + c)*K + k)*Co + o)*H + h)*W + w  -> contiguous in w.
// One thread computes 2 consecutive w pixels (float2 weight loads, coalesced).
__global__ __launch_bounds__(256) void glc2d_kernel(
    const float* __restrict__ input,
    const float* __restrict__ weights,
    float* __restrict__ out)
{
    const int t = blockIdx.x * blockDim.x + threadIdx.x;
    // bit layout: [b:1][o:5][h:6][w2:5]  -> 2*32*64*32 = 131072 threads
    const int w2 = t & (W / 2 - 1);        // 0..31
    const int h  = (t >> 5) & (H - 1);     // 0..63
    const int o  = (t >> 11) & (Co - 1);   // 0..31
    const int b  = t >> 16;                // 0..1
    const int w0 = w2 * 2;

    float acc0 = 0.f, acc1 = 0.f;

    const size_t plane = (size_t)H * W;
    // weights base for (b, c=0, k=0, o, h, w0)
    const float* wp = weights + (((size_t)b * Ci * K + 0) * Co + o) * plane
                              + (size_t)h * W + w0;
    const float* ip = input + (size_t)b * Ci * plane;
    const size_t cstride = (size_t)K * Co * plane;   // advance one c
    const size_t kstride = (size_t)Co * plane;       // advance one k

    for (int c = 0; c < Ci; ++c) {
        // Input patch rows h-1..h+1, cols w0-1..w0+2 (zero padded)
        float in_r[3][4];
        const float* icp = ip + (size_t)c * plane;
#pragma unroll
        for (int r = 0; r < 3; ++r) {
            const int hh = h + r - 1;
            const bool hok = (hh >= 0) & (hh < H);
#pragma unroll
            for (int q = 0; q < 4; ++q) {
                const int ww = w0 + q - 1;
                const bool ok = hok & (ww >= 0) & (ww < W);
                in_r[r][q] = ok ? icp[(size_t)hh * W + ww] : 0.f;
            }
        }
        const float* wcp = wp + (size_t)c * cstride;
#pragma unroll
        for (int k = 0; k < 9; ++k) {
            const int r = k / 3;
            const int q = k % 3;
            const float2 wv = *reinterpret_cast<const float2*>(wcp + (size_t)k * kstride);
            acc0 = fmaf(in_r[r][q],     wv.x, acc0);
            acc1 = fmaf(in_r[r][q + 1], wv.y, acc1);
        }
    }

    const size_t oidx = ((((size_t)b * Co + o) * H + h) * W + w0);
    float2 ov;
    ov.x = acc0;
    ov.y = acc1;
    *reinterpret_cast<float2*>(out + oidx) = ov;
}

extern "C" void kernel_launch(void* const* d_in, const int* in_sizes, int n_in,
                              void* d_out, int out_size, void* d_ws, size_t ws_size,
                              hipStream_t stream)
{
    const float* input   = (const float*)d_in[0];
    const float* weights = (const float*)d_in[1];
    float* out = (float*)d_out;

    const int total_threads = B * Co * H * (W / 2);  // 131072
    const int block = 256;
    const int grid = total_threads / block;          // 512
    glc2d_kernel<<<grid, block, 0, stream>>>(input, weights, out);
}

// Round 2
// 63.549 us; speedup vs baseline: 1.0465x; 1.0465x over previous
//
#include <hip/hip_runtime.h>

// Problem constants (from reference setup_inputs)
constexpr int B  = 2;
constexpr int Ci = 32;
constexpr int K  = 9;   // 3x3
constexpr int Co = 32;
constexpr int H  = 64;
constexpr int W  = 64;

// out[b,o,h,w] = sum_{c,k} x[b,c,h+kh-1,w+kw-1] * wt[b,c,k,o,h,w]
// weights layout: ((((b*Ci + c)*K + k)*Co + o)*H + h)*W + w  -> contiguous in w.
// One thread computes 4 consecutive w pixels (float4 weight loads, 16B/lane).
// Input halo columns (w0-1, w0+4) come from neighbor lanes via shuffles; the
// 16-lane w-group boundary coincides exactly with the zero-padding boundary.
__global__ __launch_bounds__(256) void glc2d_kernel(
    const float* __restrict__ input,
    const float* __restrict__ weights,
    float* __restrict__ out)
{
    const int t = blockIdx.x * blockDim.x + threadIdx.x;
    // bit layout: [b:1][o:5][h:6][w4:4] -> 2*32*64*16 = 65536 threads
    const int w4 = t & 15;                 // 0..15 (16 groups of 4 pixels)
    const int h  = (t >> 4) & (H - 1);     // 0..63
    const int o  = (t >> 10) & (Co - 1);   // 0..31
    const int b  = t >> 15;                // 0..1
    const int w0 = w4 * 4;

    float acc0 = 0.f, acc1 = 0.f, acc2 = 0.f, acc3 = 0.f;

    const size_t plane = (size_t)H * W;
    // weights base for (b, c=0, k=0, o, h, w0)
    const float* wp = weights + (((size_t)b * Ci * K) * Co + o) * plane
                              + (size_t)h * W + w0;
    const float* ip = input + (size_t)b * Ci * plane + (size_t)h * W + w0;
    const size_t cstride = (size_t)K * Co * plane;   // advance one c (weights)
    const size_t kstride = (size_t)Co * plane;       // advance one k (weights)

    const bool has_left  = (w4 > 0);
    const bool has_right = (w4 < 15);

#pragma unroll 2
    for (int c = 0; c < Ci; ++c) {
        // --- weight loads first: 9 independent float4 HBM streams ---
        const float* wcp = wp + (size_t)c * cstride;
        float4 wv[9];
#pragma unroll
        for (int k = 0; k < 9; ++k) {
            wv[k] = *reinterpret_cast<const float4*>(wcp + (size_t)k * kstride);
        }

        // --- input rows h-1..h+1, cols w0-1..w0+4 (zero padded) ---
        const float* icp = ip + (size_t)c * plane;
        float row[3][6];
#pragma unroll
        for (int r = 0; r < 3; ++r) {
            const int hh = h + r - 1;
            const bool hok = (hh >= 0) & (hh < H);
            float4 v;
            if (hok) {
                v = *reinterpret_cast<const float4*>(icp + (size_t)(r - 1) * W);
            } else {
                v = make_float4(0.f, 0.f, 0.f, 0.f);
            }
            const float lf = __shfl_up(v.w, 1);    // neighbor lane's col w0-1
            const float rt = __shfl_down(v.x, 1);  // neighbor lane's col w0+4
            row[r][0] = has_left  ? lf : 0.f;
            row[r][1] = v.x;
            row[r][2] = v.y;
            row[r][3] = v.z;
            row[r][4] = v.w;
            row[r][5] = has_right ? rt : 0.f;
        }

        // --- 36 FMAs: out pixel p uses input col (p + q) of row r for tap k=3r+q
#pragma unroll
        for (int k = 0; k < 9; ++k) {
            const int r = k / 3;
            const int q = k % 3;
            acc0 = fmaf(row[r][q + 0], wv[k].x, acc0);
            acc1 = fmaf(row[r][q + 1], wv[k].y, acc1);
            acc2 = fmaf(row[r][q + 2], wv[k].z, acc2);
            acc3 = fmaf(row[r][q + 3], wv[k].w, acc3);
        }
    }

    const size_t oidx = ((((size_t)b * Co + o) * H + h) * W + w0);
    float4 ov;
    ov.x = acc0; ov.y = acc1; ov.z = acc2; ov.w = acc3;
    *reinterpret_cast<float4*>(out + oidx) = ov;
}

extern "C" void kernel_launch(void* const* d_in, const int* in_sizes, int n_in,
                              void* d_out, int out_size, void* d_ws, size_t ws_size,
                              hipStream_t stream)
{
    const float* input   = (const float*)d_in[0];
    const float* weights = (const float*)d_in[1];
    float* out = (float*)d_out;

    const int total_threads = B * Co * H * (W / 4);  // 65536
    const int block = 256;
    const int grid = total_threads / block;          // 256
    glc2d_kernel<<<grid, block, 0, stream>>>(input, weights, out);
}

// Round 3
// 53.193 us; speedup vs baseline: 1.2503x; 1.1947x over previous
//
#include <hip/hip_runtime.h>

// Problem constants (from reference setup_inputs)
constexpr int B  = 2;
constexpr int Ci = 32;
constexpr int K  = 9;   // 3x3
constexpr int Co = 32;
constexpr int H  = 64;
constexpr int W  = 64;

// out[b,o,h,w] = sum_{c,k} x[b,c,h+kh-1,w+kw-1] * wt[b,c,k,o,h,w]
// weights layout: ((((b*Ci + c)*K + k)*Co + o)*H + h)*W + w  -> contiguous in w.
//
// One output-quad (4 consecutive w pixels) is computed by TWO threads, each
// summing half the input channels (c 0-15 / 16-31); partials combined via a
// 2-way LDS reduction. This doubles wave count (2 waves/SIMD) vs one thread
// per quad while keeping 16 B/lane float4 weight streams.
__global__ __launch_bounds__(256) void glc2d_kernel(
    const float* __restrict__ input,
    const float* __restrict__ weights,
    float* __restrict__ out)
{
    __shared__ float4 partial[128];

    const int tid   = threadIdx.x;
    const int g     = blockIdx.x * 128 + (tid & 127);  // output-quad index
    const int chalf = tid >> 7;                        // 0: c 0-15, 1: c 16-31

    // bit layout of g: [b:1][o:5][h:6][w4:4]  -> 65536 quads
    const int w4 = g & 15;                 // 0..15 (16 groups of 4 pixels)
    const int h  = (g >> 4) & (H - 1);     // 0..63
    const int o  = (g >> 10) & (Co - 1);   // 0..31
    const int b  = g >> 15;                // 0..1
    const int w0 = w4 * 4;

    float acc0 = 0.f, acc1 = 0.f, acc2 = 0.f, acc3 = 0.f;

    const size_t plane = (size_t)H * W;
    const size_t cstride = (size_t)K * Co * plane;   // advance one c (weights)
    const size_t kstride = (size_t)Co * plane;       // advance one k (weights)

    // bases at (b, c=chalf*16, k=0, o, h, w0)
    const int c0 = chalf * 16;
    const float* wp = weights + ((size_t)b * Ci * K + (size_t)c0 * K) * Co * plane
                              + (size_t)o * plane + (size_t)h * W + w0;
    const float* ip = input + ((size_t)b * Ci + c0) * plane + (size_t)h * W + w0;

    const bool has_left  = (w4 > 0);
    const bool has_right = (w4 < 15);

#pragma unroll 2
    for (int c = 0; c < 16; ++c) {
        // --- weight loads first: 9 independent float4 HBM streams ---
        const float* wcp = wp + (size_t)c * cstride;
        float4 wv[9];
#pragma unroll
        for (int k = 0; k < 9; ++k) {
            wv[k] = *reinterpret_cast<const float4*>(wcp + (size_t)k * kstride);
        }

        // --- input rows h-1..h+1, cols w0-1..w0+4 (zero padded) ---
        const float* icp = ip + (size_t)c * plane;
        float row[3][6];
#pragma unroll
        for (int r = 0; r < 3; ++r) {
            const int hh = h + r - 1;
            const bool hok = (hh >= 0) & (hh < H);
            float4 v;
            if (hok) {
                v = *reinterpret_cast<const float4*>(icp + (size_t)(r - 1) * W);
            } else {
                v = make_float4(0.f, 0.f, 0.f, 0.f);
            }
            const float lf = __shfl_up(v.w, 1);    // neighbor lane's col w0-1
            const float rt = __shfl_down(v.x, 1);  // neighbor lane's col w0+4
            row[r][0] = has_left  ? lf : 0.f;
            row[r][1] = v.x;
            row[r][2] = v.y;
            row[r][3] = v.z;
            row[r][4] = v.w;
            row[r][5] = has_right ? rt : 0.f;
        }

        // --- 36 FMAs: out pixel p uses input col (p + q) of row r for tap k=3r+q
#pragma unroll
        for (int k = 0; k < 9; ++k) {
            const int r = k / 3;
            const int q = k % 3;
            acc0 = fmaf(row[r][q + 0], wv[k].x, acc0);
            acc1 = fmaf(row[r][q + 1], wv[k].y, acc1);
            acc2 = fmaf(row[r][q + 2], wv[k].z, acc2);
            acc3 = fmaf(row[r][q + 3], wv[k].w, acc3);
        }
    }

    // --- 2-way reduction across c-halves via LDS ---
    if (chalf) {
        partial[tid & 127] = make_float4(acc0, acc1, acc2, acc3);
    }
    __syncthreads();
    if (!chalf) {
        const float4 p = partial[tid];
        const size_t oidx = ((((size_t)b * Co + o) * H + h) * W + w0);
        float4 ov;
        ov.x = acc0 + p.x;
        ov.y = acc1 + p.y;
        ov.z = acc2 + p.z;
        ov.w = acc3 + p.w;
        *reinterpret_cast<float4*>(out + oidx) = ov;
    }
}

extern "C" void kernel_launch(void* const* d_in, const int* in_sizes, int n_in,
                              void* d_out, int out_size, void* d_ws, size_t ws_size,
                              hipStream_t stream)
{
    const float* input   = (const float*)d_in[0];
    const float* weights = (const float*)d_in[1];
    float* out = (float*)d_out;

    const int total_threads = B * Co * H * (W / 4) * 2;  // 131072 (2 c-halves)
    const int block = 256;
    const int grid = total_threads / block;              // 512
    glc2d_kernel<<<grid, block, 0, stream>>>(input, weights, out);
}

// Round 4
// 50.677 us; speedup vs baseline: 1.3124x; 1.0496x over previous
//
#include <hip/hip_runtime.h>

// Problem constants (from reference setup_inputs)
constexpr int B  = 2;
constexpr int Ci = 32;
constexpr int K  = 9;   // 3x3
constexpr int Co = 32;
constexpr int H  = 64;
constexpr int W  = 64;

typedef float f32x4 __attribute__((ext_vector_type(4)));

// out[b,o,h,w] = sum_{c,k} x[b,c,h+kh-1,w+kw-1] * wt[b,c,k,o,h,w]
// weights layout: ((((b*Ci + c)*K + k)*Co + o)*H + h)*W + w  -> contiguous in w.
//
// One output-quad (4 consecutive w pixels) is computed by FOUR threads, each
// summing a quarter of the input channels (8 c each); partials combined via a
// 4-way LDS reduction. 262144 threads = 4 waves/SIMD for deep memory TLP.
// Weight loads are nontemporal (stream-once; keep input L2-resident).
__global__ __launch_bounds__(256) void glc2d_kernel(
    const float* __restrict__ input,
    const float* __restrict__ weights,
    float* __restrict__ out)
{
    __shared__ f32x4 partial[3][64];

    const int tid = threadIdx.x;
    const int q   = tid & 63;                    // quad slot within block
    const int cq  = tid >> 6;                    // c-quarter 0..3
    const int g   = blockIdx.x * 64 + q;         // output-quad index

    // bit layout of g: [b:1][o:5][h:6][w4:4]  -> 65536 quads
    const int w4 = g & 15;                 // 0..15 (16 groups of 4 pixels)
    const int h  = (g >> 4) & (H - 1);     // 0..63
    const int o  = (g >> 10) & (Co - 1);   // 0..31
    const int b  = g >> 15;                // 0..1
    const int w0 = w4 * 4;

    float acc0 = 0.f, acc1 = 0.f, acc2 = 0.f, acc3 = 0.f;

    const size_t plane = (size_t)H * W;
    const size_t cstride = (size_t)K * Co * plane;   // advance one c (weights)
    const size_t kstride = (size_t)Co * plane;       // advance one k (weights)

    // bases at (b, c=cq*8, k=0, o, h, w0)
    const int c0 = cq * 8;
    const float* wp = weights + ((size_t)(b * Ci + c0) * K) * Co * plane
                              + (size_t)o * plane + (size_t)h * W + w0;
    const float* ip = input + ((size_t)b * Ci + c0) * plane + (size_t)h * W + w0;

    const bool has_left  = (w4 > 0);
    const bool has_right = (w4 < 15);

#pragma unroll 2
    for (int c = 0; c < 8; ++c) {
        // --- weight loads first: 9 independent float4 HBM streams (NT) ---
        const float* wcp = wp + (size_t)c * cstride;
        f32x4 wv[9];
#pragma unroll
        for (int k = 0; k < 9; ++k) {
            wv[k] = __builtin_nontemporal_load(
                reinterpret_cast<const f32x4*>(wcp + (size_t)k * kstride));
        }

        // --- input rows h-1..h+1, cols w0-1..w0+4 (zero padded) ---
        const float* icp = ip + (size_t)c * plane;
        float row[3][6];
#pragma unroll
        for (int r = 0; r < 3; ++r) {
            const int hh = h + r - 1;
            const bool hok = (hh >= 0) & (hh < H);
            f32x4 v;
            if (hok) {
                v = *reinterpret_cast<const f32x4*>(icp + (size_t)(r - 1) * W);
            } else {
                v = (f32x4)(0.f);
            }
            const float lf = __shfl_up(v.w, 1);    // neighbor lane's col w0-1
            const float rt = __shfl_down(v.x, 1);  // neighbor lane's col w0+4
            row[r][0] = has_left  ? lf : 0.f;
            row[r][1] = v.x;
            row[r][2] = v.y;
            row[r][3] = v.z;
            row[r][4] = v.w;
            row[r][5] = has_right ? rt : 0.f;
        }

        // --- 36 FMAs: out pixel p uses input col (p + q) of row r for tap k=3r+q
#pragma unroll
        for (int k = 0; k < 9; ++k) {
            const int r = k / 3;
            const int qq = k % 3;
            acc0 = fmaf(row[r][qq + 0], wv[k].x, acc0);
            acc1 = fmaf(row[r][qq + 1], wv[k].y, acc1);
            acc2 = fmaf(row[r][qq + 2], wv[k].z, acc2);
            acc3 = fmaf(row[r][qq + 3], wv[k].w, acc3);
        }
    }

    // --- 4-way reduction across c-quarters via LDS ---
    f32x4 acc;
    acc.x = acc0; acc.y = acc1; acc.z = acc2; acc.w = acc3;
    if (cq) {
        partial[cq - 1][q] = acc;
    }
    __syncthreads();
    if (!cq) {
        const f32x4 p0 = partial[0][q];
        const f32x4 p1 = partial[1][q];
        const f32x4 p2 = partial[2][q];
        acc += p0 + p1 + p2;
        const size_t oidx = ((((size_t)b * Co + o) * H + h) * W + w0);
        *reinterpret_cast<f32x4*>(out + oidx) = acc;
    }
}

extern "C" void kernel_launch(void* const* d_in, const int* in_sizes, int n_in,
                              void* d_out, int out_size, void* d_ws, size_t ws_size,
                              hipStream_t stream)
{
    const float* input   = (const float*)d_in[0];
    const float* weights = (const float*)d_in[1];
    float* out = (float*)d_out;

    const int total_threads = B * Co * H * (W / 4) * 4;  // 262144 (4 c-quarters)
    const int block = 256;
    const int grid = total_threads / block;              // 1024
    glc2d_kernel<<<grid, block, 0, stream>>>(input, weights, out);
}